// Round 2
// baseline (128.495 us; speedup 1.0000x reference)
//
#include <hip/hip_runtime.h>

// Problem constants (from reference): M=8 samples, N=4096, K=16 filters.
#define NN 4096
#define MM 8
#define KK 16

// Kernel 1: col[m] = sum_j L[j, m]  (column sums of row-major L[N][N]).
// float4 loads: grid (4 col-blocks of 256 float4, 64 row-blocks of 64 rows).
// Each thread owns one float4 column-slot, accumulates 64 rows in registers,
// then 4 atomicAdds (64 contenders per address — negligible).
__global__ void __launch_bounds__(256) colsum_kernel(const float* __restrict__ L,
                                                     float* __restrict__ col) {
    const int m4 = blockIdx.x * 256 + threadIdx.x;   // float4 column index 0..1023
    const int r0 = blockIdx.y * 64;
    const float4* __restrict__ L4 = reinterpret_cast<const float4*>(L);
    float4 acc = {0.f, 0.f, 0.f, 0.f};
#pragma unroll 8
    for (int j = 0; j < 64; ++j) {
        const float4 v = L4[(size_t)(r0 + j) * (NN / 4) + m4];
        acc.x += v.x; acc.y += v.y; acc.z += v.z; acc.w += v.w;
    }
    atomicAdd(&col[m4 * 4 + 0], acc.x);
    atomicAdd(&col[m4 * 4 + 1], acc.y);
    atomicAdd(&col[m4 * 4 + 2], acc.z);
    atomicAdd(&col[m4 * 4 + 3], acc.w);
}

// Kernel 2: per output row (b,i):
//   s = dot(x[b,i,:], col);  out[b,i] = sum_k tanh(W[k,i] * s)
// 4 consecutive rows per wave: one col float4 (L1-hit) amortized over 4 x
// float4 loads (HBM), 4 independent accumulator chains for ILP.
// Epilogue: butterfly-reduce all 4 accs (every lane holds s0..s3), then
// lane group r = lane>>4 evaluates the 16 filters of row r and reduces
// within its 16-lane group.
__global__ void __launch_bounds__(256) conv_kernel(const float* __restrict__ x,
                                                   const float* __restrict__ col,
                                                   const float* __restrict__ W,
                                                   float* __restrict__ out) {
    const int wave = threadIdx.x >> 6;               // 0..3
    const int lane = threadIdx.x & 63;
    const int row0 = (blockIdx.x * 4 + wave) * 4;    // 4 consecutive rows
    const float4* __restrict__ cv = reinterpret_cast<const float4*>(col);
    const float4* __restrict__ x4 = reinterpret_cast<const float4*>(x);
    const size_t base = (size_t)row0 * (NN / 4);

    float a0 = 0.f, a1 = 0.f, a2 = 0.f, a3 = 0.f;
#pragma unroll 4
    for (int it = 0; it < NN / 4 / 64; ++it) {       // 16 iterations
        const int o = it * 64 + lane;
        const float4 c  = cv[o];
        const float4 v0 = x4[base + 0 * (NN / 4) + o];
        const float4 v1 = x4[base + 1 * (NN / 4) + o];
        const float4 v2 = x4[base + 2 * (NN / 4) + o];
        const float4 v3 = x4[base + 3 * (NN / 4) + o];
        a0 += v0.x * c.x + v0.y * c.y + v0.z * c.z + v0.w * c.w;
        a1 += v1.x * c.x + v1.y * c.y + v1.z * c.z + v1.w * c.w;
        a2 += v2.x * c.x + v2.y * c.y + v2.z * c.z + v2.w * c.w;
        a3 += v3.x * c.x + v3.y * c.y + v3.z * c.z + v3.w * c.w;
    }

    // Full-wave butterfly: every lane ends with the complete dot product
    // for all 4 rows.
#pragma unroll
    for (int off = 32; off >= 1; off >>= 1) {
        a0 += __shfl_xor(a0, off, 64);
        a1 += __shfl_xor(a1, off, 64);
        a2 += __shfl_xor(a2, off, 64);
        a3 += __shfl_xor(a3, off, 64);
    }

    const int r = lane >> 4;                          // which row this group handles
    const int k = lane & 15;                          // which filter
    const float s = (r == 0) ? a0 : (r == 1) ? a1 : (r == 2) ? a2 : a3;
    const int row = row0 + r;
    const int i = row & (NN - 1);
    float v = tanhf(W[k * NN + i] * s);
#pragma unroll
    for (int off = 8; off >= 1; off >>= 1)
        v += __shfl_down(v, off, 16);                 // reduce within 16-lane group
    if (k == 0) out[row] = v;
}

extern "C" void kernel_launch(void* const* d_in, const int* in_sizes, int n_in,
                              void* d_out, int out_size, void* d_ws, size_t ws_size,
                              hipStream_t stream) {
    const float* x = (const float*)d_in[0];  // [M, N, N]
    const float* L = (const float*)d_in[1];  // [N, N]
    const float* W = (const float*)d_in[2];  // [K, N]
    float* out = (float*)d_out;              // [M, N] fp32
    float* col = (float*)d_ws;               // [N] scratch

    // col must be zeroed every call (ws is poisoned once, never re-poisoned).
    hipMemsetAsync(col, 0, NN * sizeof(float), stream);

    colsum_kernel<<<dim3(4, 64), 256, 0, stream>>>(L, col);
    conv_kernel<<<(MM * NN) / 16, 256, 0, stream>>>(x, col, W, out);
}

// Round 4
// 123.679 us; speedup vs baseline: 1.0389x; 1.0389x over previous
//
#include <hip/hip_runtime.h>

// Problem constants (from reference): M=8 samples, N=4096, K=16 filters.
#define NN 4096
#define MM 8
#define KK 16

// Native clang vector type — __builtin_nontemporal_load requires a true
// vector-of-float type (HIP's float4 struct is rejected).
typedef float v4f __attribute__((ext_vector_type(4)));

// Kernel 1: col[m] = sum_j L[j, m]  (column sums of row-major L[N][N]).
// float4 nontemporal loads; grid (4 col-blocks x 256 row-blocks) = 1024
// blocks -> 4 blocks/CU, 16 waves/CU for latency hiding. Each thread owns
// one float4 column-slot, accumulates 16 rows, then 4 atomicAdds
// (256 contenders per address, spread over 4096 addresses — negligible).
__global__ void __launch_bounds__(256) colsum_kernel(const float* __restrict__ L,
                                                     float* __restrict__ col) {
    const int m4 = blockIdx.x * 256 + threadIdx.x;   // float4 column index 0..1023
    const int r0 = blockIdx.y * 16;
    const v4f* __restrict__ L4 = reinterpret_cast<const v4f*>(L);
    v4f acc = {0.f, 0.f, 0.f, 0.f};
#pragma unroll
    for (int j = 0; j < 16; ++j) {
        const v4f v = __builtin_nontemporal_load(&L4[(size_t)(r0 + j) * (NN / 4) + m4]);
        acc += v;
    }
    atomicAdd(&col[m4 * 4 + 0], acc.x);
    atomicAdd(&col[m4 * 4 + 1], acc.y);
    atomicAdd(&col[m4 * 4 + 2], acc.z);
    atomicAdd(&col[m4 * 4 + 3], acc.w);
}

// Kernel 2: per output row (b,i):
//   s = dot(x[b,i,:], col);  out[b,i] = sum_k tanh(W[k,i] * s)
// One 64-lane wave per row (round-1 structure — fastest measured). x is
// stream-once -> nontemporal; col stays cached (L1-resident 16 KB).
__global__ void __launch_bounds__(256) conv_kernel(const float* __restrict__ x,
                                                   const float* __restrict__ col,
                                                   const float* __restrict__ W,
                                                   float* __restrict__ out) {
    const int wave = threadIdx.x >> 6;         // 0..3
    const int lane = threadIdx.x & 63;
    const int row  = blockIdx.x * 4 + wave;    // 0 .. 32767  (= b*NN + i)
    const int i    = row & (NN - 1);

    const v4f* __restrict__ xr = reinterpret_cast<const v4f*>(x) + (size_t)row * (NN / 4);
    const v4f* __restrict__ cv = reinterpret_cast<const v4f*>(col);

    float acc = 0.f;
#pragma unroll
    for (int it = 0; it < NN / 4 / 64; ++it) {      // 16 iterations
        const v4f a = __builtin_nontemporal_load(&xr[it * 64 + lane]);
        const v4f c = cv[it * 64 + lane];
        const v4f p = a * c;
        acc += p.x + p.y + p.z + p.w;
    }

    // Butterfly reduce: every lane ends with the full dot product s.
#pragma unroll
    for (int off = 32; off >= 1; off >>= 1)
        acc += __shfl_xor(acc, off, 64);

    // Lanes 0..15 each evaluate one filter; lanes 16..63 contribute 0.
    float r = 0.f;
    if (lane < KK) r = tanhf(W[lane * NN + i] * acc);
#pragma unroll
    for (int off = 8; off >= 1; off >>= 1)
        r += __shfl_down(r, off, 64);

    if (lane == 0) out[row] = r;
}

extern "C" void kernel_launch(void* const* d_in, const int* in_sizes, int n_in,
                              void* d_out, int out_size, void* d_ws, size_t ws_size,
                              hipStream_t stream) {
    const float* x = (const float*)d_in[0];  // [M, N, N]
    const float* L = (const float*)d_in[1];  // [N, N]
    const float* W = (const float*)d_in[2];  // [K, N]
    float* out = (float*)d_out;              // [M, N] fp32
    float* col = (float*)d_ws;               // [N] scratch

    // col must be zeroed every call (ws is poisoned once, never re-poisoned).
    (void)hipMemsetAsync(col, 0, NN * sizeof(float), stream);

    colsum_kernel<<<dim3(4, 256), 256, 0, stream>>>(L, col);
    conv_kernel<<<(MM * NN) / 4, 256, 0, stream>>>(x, col, W, out);
}

// Round 6
// 111.637 us; speedup vs baseline: 1.1510x; 1.1079x over previous
//
#include <hip/hip_runtime.h>

// Problem constants (from reference): M=8 samples, N=4096, K=16 filters.
#define NN 4096
#define MM 8
#define KK 16

// Native clang vector type (HIP float4 struct is rejected by some builtins,
// and ext vectors get clean componentwise ops).
typedef float v4f __attribute__((ext_vector_type(4)));

// ws layout (all write-before-read every call; no memset needed):
//   col     @ 0                : 4096 floats (16 KB)
//   partial @ 4096             : 64 x 4096 floats (1 MB), partial[rg][m]
//   Wt      @ 4096 + 64*4096   : 4096 x 16 floats (256 KB), Wt[i][k]
#define WS_COL     0
#define WS_PARTIAL 4096
#define WS_WT      (4096 + 64 * 4096)

// Stage 1: partial[rg][m] = sum of 64 rows of L in row-group rg, column m.
// Grid (4 col-stripes x 64 row-groups) = 256 blocks. float4 loads + float4
// stores, zero atomics, zero init. Each block reads 256 KB of L.
__global__ void __launch_bounds__(256) colsum_stage1(const float* __restrict__ L,
                                                     float* __restrict__ ws) {
    const int m4 = blockIdx.x * 256 + threadIdx.x;   // float4 column slot 0..1023
    const int r0 = blockIdx.y * 64;
    const v4f* __restrict__ L4 = reinterpret_cast<const v4f*>(L);
    v4f acc = {0.f, 0.f, 0.f, 0.f};
#pragma unroll 8
    for (int j = 0; j < 64; ++j) {
        acc += L4[(size_t)(r0 + j) * (NN / 4) + m4];
    }
    reinterpret_cast<v4f*>(ws + WS_PARTIAL)[blockIdx.y * (NN / 4) + m4] = acc;
}

// Stage 2: 16 blocks.
//   blocks 0..3  : col[m] = sum_rg partial[rg][m]   (1 MB, L2-resident)
//   blocks 4..15 : Wt[i][k] = W[k][i]               (256 KB transpose)
__global__ void __launch_bounds__(256) colsum_stage2(const float* __restrict__ W,
                                                     float* __restrict__ ws) {
    const int b = blockIdx.x;
    const int t = threadIdx.x;
    if (b < 4) {
        const int slot = b * 256 + t;                // float4 column slot 0..1023
        const v4f* __restrict__ p4 = reinterpret_cast<const v4f*>(ws + WS_PARTIAL);
        v4f acc = {0.f, 0.f, 0.f, 0.f};
#pragma unroll 8
        for (int j = 0; j < 64; ++j) {
            acc += p4[j * (NN / 4) + slot];
        }
        reinterpret_cast<v4f*>(ws + WS_COL)[slot] = acc;
    } else {
        // 12 blocks x 256 threads = 3072 threads over 65536 elements.
        float* __restrict__ Wt = ws + WS_WT;
        for (int o = (b - 4) * 256 + t; o < NN * KK; o += 12 * 256) {
            const int i = o >> 4;                    // simplex index
            const int k = o & 15;                    // filter index
            Wt[o] = W[k * NN + i];
        }
    }
}

// Stage 3 (conv): per output row (b,i):
//   s = dot(x[b,i,:], col);  out[b,i] = sum_k tanh(Wt[i][k] * s)
// One 64-lane wave per row (round-1 structure — fastest measured).
// col is L1-resident (16 KB); Wt read is one coalesced 64 B line per row.
__global__ void __launch_bounds__(256) conv_kernel(const float* __restrict__ x,
                                                   const float* __restrict__ ws,
                                                   float* __restrict__ out) {
    const int wave = threadIdx.x >> 6;         // 0..3
    const int lane = threadIdx.x & 63;
    const int row  = blockIdx.x * 4 + wave;    // 0 .. 32767  (= b*NN + i)
    const int i    = row & (NN - 1);

    const v4f* __restrict__ xr = reinterpret_cast<const v4f*>(x) + (size_t)row * (NN / 4);
    const v4f* __restrict__ cv = reinterpret_cast<const v4f*>(ws + WS_COL);

    float acc = 0.f;
#pragma unroll
    for (int it = 0; it < NN / 4 / 64; ++it) {      // 16 iterations
        const v4f a = xr[it * 64 + lane];
        const v4f c = cv[it * 64 + lane];
        const v4f p = a * c;
        acc += p.x + p.y + p.z + p.w;
    }

    // Butterfly reduce: every lane ends with the full dot product s.
#pragma unroll
    for (int off = 32; off >= 1; off >>= 1)
        acc += __shfl_xor(acc, off, 64);

    // Lanes 0..15 each evaluate one filter (coalesced 64B Wt line).
    float r = 0.f;
    if (lane < KK) r = tanhf((ws + WS_WT)[i * KK + lane] * acc);
#pragma unroll
    for (int off = 8; off >= 1; off >>= 1)
        r += __shfl_down(r, off, 64);

    if (lane == 0) out[row] = r;
}

extern "C" void kernel_launch(void* const* d_in, const int* in_sizes, int n_in,
                              void* d_out, int out_size, void* d_ws, size_t ws_size,
                              hipStream_t stream) {
    const float* x = (const float*)d_in[0];  // [M, N, N]
    const float* L = (const float*)d_in[1];  // [N, N]
    const float* W = (const float*)d_in[2];  // [K, N]
    float* out = (float*)d_out;              // [M, N] fp32
    float* ws  = (float*)d_ws;               // scratch (col | partial | Wt)

    colsum_stage1<<<dim3(4, 64), 256, 0, stream>>>(L, ws);
    colsum_stage2<<<16, 256, 0, stream>>>(W, ws);
    conv_kernel<<<(MM * NN) / 4, 256, 0, stream>>>(x, ws, out);
}

// Round 7
// 101.525 us; speedup vs baseline: 1.2656x; 1.0996x over previous
//
#include <hip/hip_runtime.h>

// Problem constants (from reference): M=8 samples, N=4096, K=16 filters.
#define NN 4096
#define MM 8
#define KK 16

// Native clang vector type (HIP float4 struct is rejected by __builtin_nontemporal_load,
// and ext vectors get clean componentwise ops).
typedef float v4f __attribute__((ext_vector_type(4)));

// ws layout (all write-before-read every call; no memset needed):
//   col     @ 0                : 4096 floats (16 KB)
//   partial @ 4096             : 64 x 4096 floats (1 MB), partial[rg][m]
//   Wt      @ 4096 + 64*4096   : 4096 x 16 floats (256 KB), Wt[i][k]
#define WS_COL     0
#define WS_PARTIAL 4096
#define WS_WT      (4096 + 64 * 4096)

// Stage 1: partial[rg][m] = sum of 64 rows of L in row-group rg, column m.
// Grid (4 col-stripes x 64 row-groups) = 256 blocks. float4 loads + float4
// stores, zero atomics, zero init. Each block reads 256 KB of L.
__global__ void __launch_bounds__(256) colsum_stage1(const float* __restrict__ L,
                                                     float* __restrict__ ws) {
    const int m4 = blockIdx.x * 256 + threadIdx.x;   // float4 column slot 0..1023
    const int r0 = blockIdx.y * 64;
    const v4f* __restrict__ L4 = reinterpret_cast<const v4f*>(L);
    v4f acc = {0.f, 0.f, 0.f, 0.f};
#pragma unroll 8
    for (int j = 0; j < 64; ++j) {
        acc += L4[(size_t)(r0 + j) * (NN / 4) + m4];
    }
    reinterpret_cast<v4f*>(ws + WS_PARTIAL)[blockIdx.y * (NN / 4) + m4] = acc;
}

// Stage 2: 16 blocks.
//   blocks 0..3  : col[m] = sum_rg partial[rg][m]   (1 MB, L2-resident)
//   blocks 4..15 : Wt[i][k] = W[k][i]               (256 KB transpose)
__global__ void __launch_bounds__(256) colsum_stage2(const float* __restrict__ W,
                                                     float* __restrict__ ws) {
    const int b = blockIdx.x;
    const int t = threadIdx.x;
    if (b < 4) {
        const int slot = b * 256 + t;                // float4 column slot 0..1023
        const v4f* __restrict__ p4 = reinterpret_cast<const v4f*>(ws + WS_PARTIAL);
        v4f acc = {0.f, 0.f, 0.f, 0.f};
#pragma unroll 8
        for (int j = 0; j < 64; ++j) {
            acc += p4[j * (NN / 4) + slot];
        }
        reinterpret_cast<v4f*>(ws + WS_COL)[slot] = acc;
    } else {
        // 12 blocks x 256 threads = 3072 threads over 65536 elements.
        float* __restrict__ Wt = ws + WS_WT;
        for (int o = (b - 4) * 256 + t; o < NN * KK; o += 12 * 256) {
            const int i = o >> 4;                    // simplex index
            const int k = o & 15;                    // filter index
            Wt[o] = W[k * NN + i];
        }
    }
}

// Stage 3 (conv): per output row (b,i):
//   s = dot(x[b,i,:], col);  out[b,i] = sum_k tanh(Wt[i][k] * s)
// One 64-lane wave per row. x is stream-once -> NONTEMPORAL (evict-first),
// which keeps the 16 KB col L1-resident across rows (x otherwise evicts it
// every row and col reads fall to L2).
__global__ void __launch_bounds__(256) conv_kernel(const float* __restrict__ x,
                                                   const float* __restrict__ ws,
                                                   float* __restrict__ out) {
    const int wave = threadIdx.x >> 6;         // 0..3
    const int lane = threadIdx.x & 63;
    const int row  = blockIdx.x * 4 + wave;    // 0 .. 32767  (= b*NN + i)
    const int i    = row & (NN - 1);

    const v4f* __restrict__ xr = reinterpret_cast<const v4f*>(x) + (size_t)row * (NN / 4);
    const v4f* __restrict__ cv = reinterpret_cast<const v4f*>(ws + WS_COL);

    float acc = 0.f;
#pragma unroll
    for (int it = 0; it < NN / 4 / 64; ++it) {      // 16 iterations
        const v4f a = __builtin_nontemporal_load(&xr[it * 64 + lane]);
        const v4f c = cv[it * 64 + lane];
        const v4f p = a * c;
        acc += p.x + p.y + p.z + p.w;
    }

    // Butterfly reduce: every lane ends with the full dot product s.
#pragma unroll
    for (int off = 32; off >= 1; off >>= 1)
        acc += __shfl_xor(acc, off, 64);

    // Lanes 0..15 each evaluate one filter (coalesced 64B Wt line).
    float r = 0.f;
    if (lane < KK) r = tanhf((ws + WS_WT)[i * KK + lane] * acc);
#pragma unroll
    for (int off = 8; off >= 1; off >>= 1)
        r += __shfl_down(r, off, 64);

    if (lane == 0) out[row] = r;
}

extern "C" void kernel_launch(void* const* d_in, const int* in_sizes, int n_in,
                              void* d_out, int out_size, void* d_ws, size_t ws_size,
                              hipStream_t stream) {
    const float* x = (const float*)d_in[0];  // [M, N, N]
    const float* L = (const float*)d_in[1];  // [N, N]
    const float* W = (const float*)d_in[2];  // [K, N]
    float* out = (float*)d_out;              // [M, N] fp32
    float* ws  = (float*)d_ws;               // scratch (col | partial | Wt)

    colsum_stage1<<<dim3(4, 64), 256, 0, stream>>>(L, ws);
    colsum_stage2<<<16, 256, 0, stream>>>(W, ws);
    conv_kernel<<<(MM * NN) / 4, 256, 0, stream>>>(x, ws, out);
}

// Round 8
// 100.989 us; speedup vs baseline: 1.2724x; 1.0053x over previous
//
#include <hip/hip_runtime.h>

// Problem constants (from reference): M=8 samples, N=4096, K=16 filters.
#define NN 4096
#define MM 8
#define KK 16

// Native clang vector type (HIP float4 struct is rejected by
// __builtin_nontemporal_load; ext vectors get componentwise ops).
typedef float v4f __attribute__((ext_vector_type(4)));

// ws layout (all write-before-read every call; no memset needed):
//   col     @ 0                : 4096 floats (16 KB)
//   partial @ 4096             : 64 x 4096 floats (1 MB), partial[rg][m]
//   Wt      @ 4096 + 64*4096   : 4096 x 16 floats (256 KB), Wt[i][k]
#define WS_COL     0
#define WS_PARTIAL 4096
#define WS_WT      (4096 + 64 * 4096)

// Stage 1: partial[rg][m] = sum of 64 rows of L in row-group rg, column m.
// Grid (16 col-stripes x 64 row-groups) = 1024 blocks (4/CU, 4 waves/SIMD
// — latency hiding; round-6's 256-block version ran 1 wave/SIMD).
// Each thread: 16 NT float4 loads (L is stream-once); 4 row-subgroups
// reduced via a 4 KB LDS tree; 64 lanes write one contiguous 1 KB line.
// No atomics, no init.
__global__ void __launch_bounds__(256) colsum_stage1(const float* __restrict__ L,
                                                     float* __restrict__ ws) {
    const int t  = threadIdx.x;
    const int m4 = blockIdx.x * 64 + (t & 63);        // float4 column slot 0..1023
    const int r0 = blockIdx.y * 64 + (t >> 6) * 16;   // this thread's 16 rows
    const v4f* __restrict__ L4 = reinterpret_cast<const v4f*>(L);
    v4f acc = {0.f, 0.f, 0.f, 0.f};
#pragma unroll
    for (int j = 0; j < 16; ++j) {
        acc += __builtin_nontemporal_load(&L4[(size_t)(r0 + j) * (NN / 4) + m4]);
    }
    __shared__ v4f red[256];
    red[t] = acc;
    __syncthreads();
    if (t < 64) {
        const v4f s = red[t] + red[t + 64] + red[t + 128] + red[t + 192];
        reinterpret_cast<v4f*>(ws + WS_PARTIAL)[blockIdx.y * (NN / 4) + blockIdx.x * 64 + t] = s;
    }
}

// Stage 2: 16 blocks.
//   blocks 0..3  : col[m] = sum_rg partial[rg][m]   (1 MB, cache-resident)
//   blocks 4..15 : Wt[i][k] = W[k][i]               (256 KB transpose)
__global__ void __launch_bounds__(256) colsum_stage2(const float* __restrict__ W,
                                                     float* __restrict__ ws) {
    const int b = blockIdx.x;
    const int t = threadIdx.x;
    if (b < 4) {
        const int slot = b * 256 + t;                // float4 column slot 0..1023
        const v4f* __restrict__ p4 = reinterpret_cast<const v4f*>(ws + WS_PARTIAL);
        v4f acc = {0.f, 0.f, 0.f, 0.f};
#pragma unroll 8
        for (int j = 0; j < 64; ++j) {
            acc += p4[j * (NN / 4) + slot];
        }
        reinterpret_cast<v4f*>(ws + WS_COL)[slot] = acc;
    } else {
        // 12 blocks x 256 threads = 3072 threads over 65536 elements.
        float* __restrict__ Wt = ws + WS_WT;
        for (int o = (b - 4) * 256 + t; o < NN * KK; o += 12 * 256) {
            const int i = o >> 4;                    // simplex index
            const int k = o & 15;                    // filter index
            Wt[o] = W[k * NN + i];
        }
    }
}

// Stage 3 (conv): per output row (b,i):
//   s = dot(x[b,i,:], col);  out[b,i] = sum_k tanh(Wt[i][k] * s)
// One 64-lane wave per row. x is stream-once -> NONTEMPORAL (evict-first),
// which keeps the 16 KB col L1-resident across rows (proven −10 µs in r7).
__global__ void __launch_bounds__(256) conv_kernel(const float* __restrict__ x,
                                                   const float* __restrict__ ws,
                                                   float* __restrict__ out) {
    const int wave = threadIdx.x >> 6;         // 0..3
    const int lane = threadIdx.x & 63;
    const int row  = blockIdx.x * 4 + wave;    // 0 .. 32767  (= b*NN + i)
    const int i    = row & (NN - 1);

    const v4f* __restrict__ xr = reinterpret_cast<const v4f*>(x) + (size_t)row * (NN / 4);
    const v4f* __restrict__ cv = reinterpret_cast<const v4f*>(ws + WS_COL);

    float acc = 0.f;
#pragma unroll
    for (int it = 0; it < NN / 4 / 64; ++it) {      // 16 iterations
        const v4f a = __builtin_nontemporal_load(&xr[it * 64 + lane]);
        const v4f c = cv[it * 64 + lane];
        const v4f p = a * c;
        acc += p.x + p.y + p.z + p.w;
    }

    // Butterfly reduce: every lane ends with the full dot product s.
#pragma unroll
    for (int off = 32; off >= 1; off >>= 1)
        acc += __shfl_xor(acc, off, 64);

    // Lanes 0..15 each evaluate one filter (coalesced 64B Wt line).
    float r = 0.f;
    if (lane < KK) r = tanhf((ws + WS_WT)[i * KK + lane] * acc);
#pragma unroll
    for (int off = 8; off >= 1; off >>= 1)
        r += __shfl_down(r, off, 64);

    if (lane == 0) out[row] = r;
}

extern "C" void kernel_launch(void* const* d_in, const int* in_sizes, int n_in,
                              void* d_out, int out_size, void* d_ws, size_t ws_size,
                              hipStream_t stream) {
    const float* x = (const float*)d_in[0];  // [M, N, N]
    const float* L = (const float*)d_in[1];  // [N, N]
    const float* W = (const float*)d_in[2];  // [K, N]
    float* out = (float*)d_out;              // [M, N] fp32
    float* ws  = (float*)d_ws;               // scratch (col | partial | Wt)

    colsum_stage1<<<dim3(16, 64), 256, 0, stream>>>(L, ws);
    colsum_stage2<<<16, 256, 0, stream>>>(W, ws);
    conv_kernel<<<(MM * NN) / 4, 256, 0, stream>>>(x, ws, out);
}